// Round 7
// baseline (5301.683 us; speedup 1.0000x reference)
//
#include <hip/hip_runtime.h>
#include <cstddef>

using bf16x8 = __attribute__((ext_vector_type(8))) short;
using f32x4  = __attribute__((ext_vector_type(4))) float;

constexpr int Bb = 128;
constexpr int Tt = 256;
constexpr int Hh = 1024;
constexpr int Oo = 64;
constexpr int NBLK = 104;         // 32 H1 + 32 PH + 4 PO + 32 H2U + 4 ZO
constexpr int FLAG_STRIDE = 32;   // dwords -> 128B between flags
constexpr int RS = 1048;          // LDS row stride in shorts (bank-spread, proven r0)

// ring depths
constexpr int R_H1 = 8;
constexpr int R_H2 = 16;
constexpr int R_PP = 6;           // pre2 & pg1 rings
constexpr int R_PO = 16;

// flag group bases (slot == bid for posting)
constexpr int FH1 = 0;    // 32 blocks (bid 0-31)
constexpr int FPH = 32;   // 32 blocks (bid 32-63)
constexpr int FPO = 64;   // 4 blocks  (bid 64-67)
constexpr int FH2 = 68;   // 32 blocks (bid 68-99)
constexpr int FZO = 100;  // 4 blocks  (bid 100-103)

__device__ __forceinline__ float bf2f(short s) {
  unsigned int u = ((unsigned int)(unsigned short)s) << 16;
  float f;
  __builtin_memcpy(&f, &u, 4);
  return f;
}
__device__ __forceinline__ short f2bf(float f) {
  unsigned int u;
  __builtin_memcpy(&u, &f, 4);
  u += 0x7fffu + ((u >> 16) & 1u);  // round-to-nearest-even
  return (short)(u >> 16);
}
__device__ __forceinline__ bf16x8 as_bf(int4 v) {
  union { int4 i; bf16x8 b; } u; u.i = v; return u.b;
}
__device__ __forceinline__ float ldf(const float* p) {
  return __hip_atomic_load((float*)p, __ATOMIC_RELAXED, __HIP_MEMORY_SCOPE_AGENT);
}
__device__ __forceinline__ void stf(float* p, float v) {
  __hip_atomic_store(p, v, __ATOMIC_RELAXED, __HIP_MEMORY_SCOPE_AGENT);
}
__device__ __forceinline__ unsigned ldu(const unsigned* p) {
  return __hip_atomic_load((unsigned*)p, __ATOMIC_RELAXED, __HIP_MEMORY_SCOPE_AGENT);
}

// Agent-scope (sc1) coherent 16B load — LLC-coherent (cross-XCD state reads).
#define LD16A(d, p) asm volatile("global_load_dwordx4 %0, %1, off sc1" \
                                 : "=v"(d) : "v"((const void*)(p)))

// Stage one 32-row x 1024-col bf16 state slab into LDS.
__device__ __forceinline__ void stage32(short* As, const short* src, int tid) {
  const int row = tid >> 3;          // 0..31
  const int c0  = (tid & 7) * 8;     // shorts
  const short* gp = src + (size_t)row * Hh + c0;
  short* lp = As + row * RS + c0;
  int4 r0[8], r1[8];
#pragma unroll
  for (int j = 0; j < 8; ++j) LD16A(r0[j], gp + j * 64);
#pragma unroll
  for (int j = 0; j < 8; ++j) LD16A(r1[j], gp + 512 + j * 64);
  asm volatile("s_waitcnt vmcnt(8)" ::: "memory");
#pragma unroll
  for (int j = 0; j < 8; ++j) *(int4*)(lp + j * 64) = r0[j];
  asm volatile("s_waitcnt vmcnt(0)" ::: "memory");
#pragma unroll
  for (int j = 0; j < 8; ++j) *(int4*)(lp + 512 + j * 64) = r1[j];
}

// ---- 2-stream pass (H1 / PO / ZO), 6-deep ring, proven ----
struct BPre {
  const short *bp0, *bp1;
  int4 b0v[6], b1v[6];
};
__device__ __forceinline__ void prefillB(BPre& P,
    const short* __restrict__ B0, size_t st0,
    const short* __restrict__ B1, size_t st1, int lm, int q) {
  P.bp0 = B0 + (size_t)lm * st0 + q * 8;
  P.bp1 = B1 + (size_t)lm * st1 + q * 8;
#pragma unroll
  for (int c = 0; c < 5; ++c) {
    P.b0v[c] = *(const int4*)(P.bp0 + c * 32);
    P.b1v[c] = *(const int4*)(P.bp1 + c * 32);
  }
}
__device__ __forceinline__ void pass32p(const short* As, int lm, int q,
    BPre& P, f32x4 (&acc)[2][2]) {
  const short* ap0 = As + lm * RS + q * 8;
  const short* ap1 = ap0 + 16 * RS;
#pragma unroll
  for (int c = 0; c < 32; ++c) {
    if (c + 5 < 32) {
      P.b0v[(c + 5) % 6] = *(const int4*)(P.bp0 + (c + 5) * 32);
      P.b1v[(c + 5) % 6] = *(const int4*)(P.bp1 + (c + 5) * 32);
    }
    const bf16x8 a0 = as_bf(*(const int4*)(ap0 + c * 32));
    const bf16x8 a1 = as_bf(*(const int4*)(ap1 + c * 32));
    const bf16x8 b0 = as_bf(P.b0v[c % 6]);
    const bf16x8 b1 = as_bf(P.b1v[c % 6]);
    acc[0][0] = __builtin_amdgcn_mfma_f32_16x16x32_bf16(a0, b0, acc[0][0], 0, 0, 0);
    acc[0][1] = __builtin_amdgcn_mfma_f32_16x16x32_bf16(a1, b0, acc[0][1], 0, 0, 0);
    acc[1][0] = __builtin_amdgcn_mfma_f32_16x16x32_bf16(a0, b1, acc[1][0], 0, 0, 0);
    acc[1][1] = __builtin_amdgcn_mfma_f32_16x16x32_bf16(a1, b1, acc[1][1], 0, 0, 0);
  }
}

// ---- 4-stream pass (PH / H2U merged roles), 4-deep ring ----
struct BPre4 {
  const short* bp[4];
  int4 bv[4][4];
};
__device__ __forceinline__ void prefillB4(BPre4& P,
    const short* B0, size_t st0, const short* B1, size_t st1,
    const short* B2, size_t st2, const short* B3, size_t st3, int lm, int q) {
  P.bp[0] = B0 + (size_t)lm * st0 + q * 8;
  P.bp[1] = B1 + (size_t)lm * st1 + q * 8;
  P.bp[2] = B2 + (size_t)lm * st2 + q * 8;
  P.bp[3] = B3 + (size_t)lm * st3 + q * 8;
#pragma unroll
  for (int c = 0; c < 3; ++c)
#pragma unroll
    for (int s = 0; s < 4; ++s)
      P.bv[s][c] = *(const int4*)(P.bp[s] + c * 32);
}
__device__ __forceinline__ void pass32q(const short* As, int lm, int q,
    BPre4& P, f32x4 (&acc)[4][2]) {
  const short* ap0 = As + lm * RS + q * 8;
  const short* ap1 = ap0 + 16 * RS;
#pragma unroll
  for (int c = 0; c < 32; ++c) {
    if (c + 3 < 32) {
#pragma unroll
      for (int s = 0; s < 4; ++s)
        P.bv[s][(c + 3) & 3] = *(const int4*)(P.bp[s] + (c + 3) * 32);
    }
    const bf16x8 a0 = as_bf(*(const int4*)(ap0 + c * 32));
    const bf16x8 a1 = as_bf(*(const int4*)(ap1 + c * 32));
#pragma unroll
    for (int s = 0; s < 4; ++s) {
      const bf16x8 b = as_bf(P.bv[s][c & 3]);
      acc[s][0] = __builtin_amdgcn_mfma_f32_16x16x32_bf16(a0, b, acc[s][0], 0, 0, 0);
      acc[s][1] = __builtin_amdgcn_mfma_f32_16x16x32_bf16(a1, b, acc[s][1], 0, 0, 0);
    }
  }
}

// Dataflow sync: poll one producer group's flags until all >= gen.
// Called by wave 0 only (tid < 64); mask = group_size-1 (pow2 cover).
__device__ __forceinline__ void poll_ge(const unsigned* flags, int base,
                                        int mask, unsigned gen) {
  const unsigned* f = flags + (size_t)(base + (threadIdx.x & mask)) * FLAG_STRIDE;
  while (!__all(ldu(f) >= gen))
    __builtin_amdgcn_s_sleep(2);
}

// Release: drain this wave's stores, block-sync, then tid0 posts flag.
#define POST_FLAG(GEN) do {                                                \
    asm volatile("s_waitcnt vmcnt(0) lgkmcnt(0)" ::: "memory");            \
    __syncthreads();                                                       \
    if (tid == 0)                                                          \
      __hip_atomic_store(p.flags + (size_t)bid * FLAG_STRIDE, (unsigned)(GEN), \
                         __ATOMIC_RELAXED, __HIP_MEMORY_SCOPE_AGENT);      \
  } while (0)

#define ST_BF16_PAIR(BASE, ROW, COL, HV) do {                              \
    const int _ov = __shfl_xor((int)(unsigned short)(HV), 1, 64);          \
    if ((lm & 1) == 0) {                                                   \
      const unsigned _pk = (unsigned)(unsigned short)(HV) | ((unsigned)_ov << 16); \
      __hip_atomic_store((unsigned*)((BASE) + (size_t)(ROW) * Hh + (COL)), _pk, \
                         __ATOMIC_RELAXED, __HIP_MEMORY_SCOPE_AGENT);      \
    } } while (0)

struct RP {
  short *h1ring;                    // 8  slots of [Bb x Hh] bf16
  short *h2ring;                    // 16 slots of [Bb x Hh] bf16
  float *h2f;                       // h2 f32 master (block-local tiles)
  float *pre2f;                     // 6 slots
  float *pg1f;                      // 6 slots
  float *po1f;                      // 16 slots of [Bb x Oo]
  const short* prex;
  const short *whh1, *wih2, *whh2, *wg, *wo1, *wo2;
  const float *b_ih2, *b_hh2, *bg, *bo1, *bo2;
  float* out;
  unsigned* flags;
};

// MERGED-ROLE dataflow (traffic-cut edition).
//   H1  (32 blk, 32r x 128c): h1(t) = tanh(prex + Whh1 h1(t-1))
//   PH  (32 blk, 32r x 128c, 4 streams): pre2(t)=Wih2 h1(t)+b2; pg1(t)=Wg1 h1(t)+bg
//   PO  (4 blk): po1(t) = tanh(Wo1 h1(t) + bo1)
//   H2U (32 blk, 32r x 128c, 4 streams): z2=Whh2 h2(s-1), zg=Wg2 h2(s-1);
//        u=sig(zg+pg1(s-1)), h2(s)=u*tanh(z2+pre2(s))+(1-u)h2(s-1)
//   ZO  (4 blk): out(ot) = po1(ot) + tanh(Wo2 h2(ot) + bo2)
// Narrowed polls: each wait covers only the producing group (<=8 flags).
__global__ void __launch_bounds__(256, 1) rnn_kernel(RP p) {
  __shared__ short As[32 * RS];     // 67072 B
  const int tid = threadIdx.x;
  const int lane = tid & 63;
  const int wv = tid >> 6;
  const int lm = lane & 15;
  const int q = lane >> 4;
  const int bid = blockIdx.x;

  const size_t HS = (size_t)Bb * Hh;
  const f32x4 z4 = {0.f, 0.f, 0.f, 0.f};

  if (bid < 32) {                        // ============ H1 chain ============
    const int g = bid, gm = g >> 3;
    const int mb = gm * 32, cb = (g & 7) * 128;
    const int colw = cb + wv * 32;
    const short* B0 = p.whh1 + (size_t)colw * Hh;
    const short* B1 = p.whh1 + (size_t)(colw + 16) * Hh;
    for (int t = 0; t < Tt; ++t) {
      BPre P; prefillB(P, B0, Hh, B1, Hh, lm, q);
      short prs[2][2][4];
      const short* pr = p.prex + (size_t)t * HS;
#pragma unroll
      for (int n = 0; n < 2; ++n)
#pragma unroll
        for (int rf = 0; rf < 2; ++rf)
#pragma unroll
          for (int r = 0; r < 4; ++r)
            prs[n][rf][r] = pr[(size_t)(mb + rf * 16 + q * 4 + r) * Hh + colw + n * 16 + lm];
      if (tid < 64) {
        if (t >= 1) poll_ge(p.flags, FH1 + gm * 8, 7, (unsigned)t);
        if (t >= 8) {
          poll_ge(p.flags, FPH + gm * 8, 7, (unsigned)(t - 7));
          poll_ge(p.flags, FPO + gm, 0, (unsigned)(t - 7));
        }
      }
      __syncthreads();
      const short* h1prev = p.h1ring + (size_t)((t + R_H1 - 1) % R_H1) * HS;
      stage32(As, h1prev + (size_t)mb * Hh, tid);
      __syncthreads();
      f32x4 acc[2][2]; acc[0][0] = acc[0][1] = acc[1][0] = acc[1][1] = z4;
      pass32p(As, lm, q, P, acc);
      short* h1out = p.h1ring + (size_t)(t % R_H1) * HS;
#pragma unroll
      for (int n = 0; n < 2; ++n)
#pragma unroll
        for (int rf = 0; rf < 2; ++rf)
#pragma unroll
          for (int r = 0; r < 4; ++r) {
            const int row = mb + rf * 16 + q * 4 + r;
            const int col = colw + n * 16 + lm;
            const short hv = f2bf(tanhf(acc[n][rf][r] + bf2f(prs[n][rf][r])));
            ST_BF16_PAIR(h1out, row, col, hv);
          }
      POST_FLAG(t + 1);
    }
  } else if (bid < 64) {                 // ============ PH: pre2+pg1 ============
    const int g = bid - 32, gm = g >> 3;
    const int mb = gm * 32, cb = (g & 7) * 128;
    const int colw = cb + wv * 32;
    const float b20 = p.b_ih2[colw + lm] + p.b_hh2[colw + lm];
    const float b21 = p.b_ih2[colw + 16 + lm] + p.b_hh2[colw + 16 + lm];
    const float bg0 = p.bg[colw + lm];
    const float bg1 = p.bg[colw + 16 + lm];
    for (int t = 0; t < Tt; ++t) {
      BPre4 P;
      prefillB4(P, p.wih2 + (size_t)colw * Hh, Hh,
                   p.wih2 + (size_t)(colw + 16) * Hh, Hh,
                   p.wg + (size_t)colw * (2 * Hh), 2 * Hh,
                   p.wg + (size_t)(colw + 16) * (2 * Hh), 2 * Hh, lm, q);
      if (tid < 64) {
        poll_ge(p.flags, FH1 + gm * 8, 7, (unsigned)(t + 1));
        if (t >= R_PP) poll_ge(p.flags, FH2 + g, 0, (unsigned)(t - 4));
      }
      __syncthreads();
      const short* h1cur = p.h1ring + (size_t)(t % R_H1) * HS;
      stage32(As, h1cur + (size_t)mb * Hh, tid);
      __syncthreads();
      f32x4 acc[4][2];
#pragma unroll
      for (int s = 0; s < 4; ++s) acc[s][0] = acc[s][1] = z4;
      pass32q(As, lm, q, P, acc);
      float* d2 = p.pre2f + (size_t)(t % R_PP) * HS;
      float* dg = p.pg1f + (size_t)(t % R_PP) * HS;
#pragma unroll
      for (int n = 0; n < 2; ++n)
#pragma unroll
        for (int rf = 0; rf < 2; ++rf)
#pragma unroll
          for (int r = 0; r < 4; ++r) {
            const int row = mb + rf * 16 + q * 4 + r;
            const int col = colw + n * 16 + lm;
            stf(d2 + (size_t)row * Hh + col, acc[n][rf][r] + (n ? b21 : b20));
            stf(dg + (size_t)row * Hh + col, acc[2 + n][rf][r] + (n ? bg1 : bg0));
          }
      POST_FLAG(t + 1);
    }
  } else if (bid < 68) {                 // ============ PO: po1(t) ============
    const int g = bid - 64;
    const int mb = g * 32;
    const int colw = (wv & 1) * 32;
    const float b0 = p.bo1[colw + lm];
    const float b1 = p.bo1[colw + 16 + lm];
    const short* B0 = p.wo1 + (size_t)colw * Hh;
    const short* B1 = p.wo1 + (size_t)(colw + 16) * Hh;
    for (int t = 0; t < Tt; ++t) {
      BPre P;
      if (wv < 2) prefillB(P, B0, Hh, B1, Hh, lm, q);
      if (tid < 64) {
        poll_ge(p.flags, FH1 + g * 8, 7, (unsigned)(t + 1));
        if (t >= R_PO) poll_ge(p.flags, FZO + g, 0, (unsigned)(t - 15));
      }
      __syncthreads();
      const short* h1cur = p.h1ring + (size_t)(t % R_H1) * HS;
      stage32(As, h1cur + (size_t)mb * Hh, tid);
      __syncthreads();
      if (wv < 2) {
        f32x4 acc[2][2]; acc[0][0] = acc[0][1] = acc[1][0] = acc[1][1] = z4;
        pass32p(As, lm, q, P, acc);
        float* dst = p.po1f + (size_t)(t % R_PO) * (Bb * Oo);
#pragma unroll
        for (int n = 0; n < 2; ++n)
#pragma unroll
          for (int rf = 0; rf < 2; ++rf)
#pragma unroll
            for (int r = 0; r < 4; ++r) {
              const int row = mb + rf * 16 + q * 4 + r;
              const int col = colw + n * 16 + lm;
              stf(dst + (size_t)row * Oo + col,
                  tanhf(acc[n][rf][r] + (n ? b1 : b0)));
            }
      }
      POST_FLAG(t + 1);
    }
  } else if (bid < 100) {                // ============ H2U step s ============
    const int g = bid - 68, gm = g >> 3;
    const int mb = gm * 32, cb = (g & 7) * 128;
    const int colw = cb + wv * 32;
    for (int s = 0; s < Tt; ++s) {
      BPre4 P;
      prefillB4(P, p.whh2 + (size_t)colw * Hh, Hh,
                   p.whh2 + (size_t)(colw + 16) * Hh, Hh,
                   p.wg + Hh + (size_t)colw * (2 * Hh), 2 * Hh,
                   p.wg + Hh + (size_t)(colw + 16) * (2 * Hh), 2 * Hh, lm, q);
      if (tid < 64) {
        poll_ge(p.flags, FPH + g, 0, (unsigned)(s + 1));
        if (s >= 1) poll_ge(p.flags, FH2 + gm * 8, 7, (unsigned)s);
        if (s >= R_H2) poll_ge(p.flags, FZO + gm, 0, (unsigned)(s - 15));
      }
      __syncthreads();
      float p2v[2][2][4], pg1v[2][2][4], hpv[2][2][4];
      const float* pre2s = p.pre2f + (size_t)(s % R_PP) * HS;
      const float* pg1s  = p.pg1f + (size_t)((s + R_PP - 1) % R_PP) * HS;
#pragma unroll
      for (int n = 0; n < 2; ++n)
#pragma unroll
        for (int rf = 0; rf < 2; ++rf)
#pragma unroll
          for (int r = 0; r < 4; ++r) {
            const size_t idx = (size_t)(mb + rf * 16 + q * 4 + r) * Hh + colw + n * 16 + lm;
            p2v[n][rf][r] = ldf(pre2s + idx);
            pg1v[n][rf][r] = (s > 0) ? ldf(pg1s + idx) : 0.f;
            hpv[n][rf][r] = p.h2f[idx];   // block-local plain RW
          }
      const short* h2prev = p.h2ring + (size_t)((s + R_H2 - 1) % R_H2) * HS;
      stage32(As, h2prev + (size_t)mb * Hh, tid);
      __syncthreads();
      f32x4 acc[4][2];
#pragma unroll
      for (int st = 0; st < 4; ++st) acc[st][0] = acc[st][1] = z4;
      pass32q(As, lm, q, P, acc);        // acc[0/1]=z2 n0/n1, acc[2/3]=zg n0/n1
      short* h2out = p.h2ring + (size_t)(s % R_H2) * HS;
#pragma unroll
      for (int n = 0; n < 2; ++n)
#pragma unroll
        for (int rf = 0; rf < 2; ++rf)
#pragma unroll
          for (int r = 0; r < 4; ++r) {
            const int row = mb + rf * 16 + q * 4 + r;
            const int col = colw + n * 16 + lm;
            const size_t idx = (size_t)row * Hh + col;
            const float u = (s == 0) ? 1.f
                : 1.f / (1.f + expf(-(acc[2 + n][rf][r] + pg1v[n][rf][r])));
            const float hn = tanhf(acc[n][rf][r] + p2v[n][rf][r]);
            const float nv = fmaf(u, hn - hpv[n][rf][r], hpv[n][rf][r]);
            p.h2f[idx] = nv;
            const short hv = f2bf(nv);
            ST_BF16_PAIR(h2out, row, col, hv);
          }
      POST_FLAG(s + 1);
    }
  } else {                               // ============ ZO: out(ot) ============
    const int g = bid - 100;
    const int mb = g * 32;
    const int colw = (wv & 1) * 32;
    const float b0 = p.bo2[colw + lm];
    const float b1 = p.bo2[colw + 16 + lm];
    const short* B0 = p.wo2 + (size_t)colw * Hh;
    const short* B1 = p.wo2 + (size_t)(colw + 16) * Hh;
    for (int ot = 0; ot < Tt; ++ot) {
      BPre P;
      if (wv < 2) prefillB(P, B0, Hh, B1, Hh, lm, q);
      if (tid < 64) {
        poll_ge(p.flags, FH2 + g * 8, 7, (unsigned)(ot + 1));
        poll_ge(p.flags, FPO + g, 0, (unsigned)(ot + 1));
      }
      __syncthreads();
      const float* po1s = p.po1f + (size_t)(ot % R_PO) * (Bb * Oo);
      float pv[2][2][4];
      if (wv < 2) {
#pragma unroll
        for (int n = 0; n < 2; ++n)
#pragma unroll
          for (int rf = 0; rf < 2; ++rf)
#pragma unroll
            for (int r = 0; r < 4; ++r)
              pv[n][rf][r] = ldf(po1s + (size_t)(mb + rf * 16 + q * 4 + r) * Oo
                                 + colw + n * 16 + lm);
      }
      const short* h2cur = p.h2ring + (size_t)(ot % R_H2) * HS;
      stage32(As, h2cur + (size_t)mb * Hh, tid);
      __syncthreads();
      if (wv < 2) {
        f32x4 acc[2][2]; acc[0][0] = acc[0][1] = acc[1][0] = acc[1][1] = z4;
        pass32p(As, lm, q, P, acc);
#pragma unroll
        for (int n = 0; n < 2; ++n)
#pragma unroll
          for (int rf = 0; rf < 2; ++rf)
#pragma unroll
            for (int r = 0; r < 4; ++r) {
              const int row = mb + rf * 16 + q * 4 + r;
              const int col = colw + n * 16 + lm;
              p.out[(size_t)row * (Tt * Oo) + (size_t)ot * Oo + col] =
                  pv[n][rf][r] + tanhf(acc[n][rf][r] + (n ? b1 : b0));
            }
      }
      POST_FLAG(ot + 1);
    }
  }
}

// pre_x[t][b][j] = x[b,t,:] @ W_ih1[j,:] + b_ih1[j] + b_hh1[j]  (stored bf16)
__global__ void __launch_bounds__(256) prex_kernel(
    const float* __restrict__ x, const float* __restrict__ wih1,
    const float* __restrict__ b_ih1, const float* __restrict__ b_hh1,
    short* __restrict__ prex) {
  const int tid = threadIdx.x;
  const int lane = tid & 63;
  const int wv = tid >> 6;
  const int lm = lane & 15;
  const int q = lane >> 4;
  const int bm = blockIdx.x >> 4;
  const int bn = blockIdx.x & 15;
  const int rowbase = bm * 64;
  const int col = bn * 64 + wv * 16 + lm;

  const f32x4 z4 = {0.f, 0.f, 0.f, 0.f};
  f32x4 acc[4];
#pragma unroll
  for (int mt = 0; mt < 4; ++mt) acc[mt] = z4;

#pragma unroll
  for (int kc = 0; kc < 2; ++kc) {
    const float* bp = wih1 + col * 64 + kc * 32 + q * 8;
    bf16x8 bf;
#pragma unroll
    for (int j = 0; j < 8; ++j) bf[j] = f2bf(bp[j]);
#pragma unroll
    for (int mt = 0; mt < 4; ++mt) {
      const float* ap = x + (size_t)(rowbase + mt * 16 + lm) * 64 + kc * 32 + q * 8;
      bf16x8 af;
#pragma unroll
      for (int j = 0; j < 8; ++j) af[j] = f2bf(ap[j]);
      acc[mt] = __builtin_amdgcn_mfma_f32_16x16x32_bf16(af, bf, acc[mt], 0, 0, 0);
    }
  }
  const float bia = b_ih1[col] + b_hh1[col];
#pragma unroll
  for (int mt = 0; mt < 4; ++mt) {
#pragma unroll
    for (int r = 0; r < 4; ++r) {
      const int row = rowbase + mt * 16 + q * 4 + r;  // row = b*256 + t
      const int b  = row >> 8;
      const int tt = row & 255;
      prex[((size_t)tt * Bb + b) * Hh + col] = f2bf(acc[mt][r] + bia);
    }
  }
}

__global__ void conv_kernel(const float* __restrict__ s, short* __restrict__ d, int n) {
  int i = blockIdx.x * blockDim.x + threadIdx.x;
  const int stride = gridDim.x * blockDim.x;
  for (; i < n; i += stride) d[i] = f2bf(s[i]);
}

__global__ void init_kernel(short* h1ring, short* h2ring,
                            float* h2f, unsigned* flags) {
  const int i = blockIdx.x * blockDim.x + threadIdx.x;  // exactly 128*1024
  const size_t HS = (size_t)Bb * Hh;
  h1ring[(size_t)(R_H1 - 1) * HS + i] = 0;   // h1(-1) slot
  h2ring[(size_t)(R_H2 - 1) * HS + i] = 0;   // h2(-1) slot
  h2f[i] = 0.f;
  if (i < 256) flags[i * FLAG_STRIDE] = 0u;
}

extern "C" void kernel_launch(void* const* d_in, const int* in_sizes, int n_in,
                              void* d_out, int out_size, void* d_ws, size_t ws_size,
                              hipStream_t stream) {
  (void)in_sizes; (void)n_in; (void)out_size; (void)ws_size;
  const float* x      = (const float*)d_in[0];
  const float* W_ih1  = (const float*)d_in[1];
  const float* b_ih1  = (const float*)d_in[2];
  const float* W_hh1  = (const float*)d_in[3];
  const float* b_hh1  = (const float*)d_in[4];
  const float* W_ih2  = (const float*)d_in[5];
  const float* b_ih2  = (const float*)d_in[6];
  const float* W_hh2  = (const float*)d_in[7];
  const float* b_hh2  = (const float*)d_in[8];
  const float* Wg     = (const float*)d_in[9];
  const float* bg     = (const float*)d_in[10];
  const float* Wo1    = (const float*)d_in[11];
  const float* bo1    = (const float*)d_in[12];
  const float* Wo2    = (const float*)d_in[13];
  const float* bo2    = (const float*)d_in[14];

  char* ws = (char*)d_ws;
  size_t off = 0;
  auto alloc = [&](size_t bytes) -> void* {
    void* ptr = ws + off;
    off += (bytes + 255) & ~(size_t)255;
    return ptr;
  };
  short* whh1 = (short*)alloc((size_t)Hh * Hh * 2);
  short* wih2 = (short*)alloc((size_t)Hh * Hh * 2);
  short* whh2 = (short*)alloc((size_t)Hh * Hh * 2);
  short* wg   = (short*)alloc((size_t)Hh * 2 * Hh * 2);
  short* wo1  = (short*)alloc((size_t)Oo * Hh * 2);
  short* wo2  = (short*)alloc((size_t)Oo * Hh * 2);
  short* prex = (short*)alloc((size_t)Bb * Tt * Hh * 2);
  short* h1ring = (short*)alloc((size_t)R_H1 * Bb * Hh * 2);
  short* h2ring = (short*)alloc((size_t)R_H2 * Bb * Hh * 2);
  float* h2f  = (float*)alloc((size_t)Bb * Hh * 4);
  float* pre2f= (float*)alloc((size_t)R_PP * Bb * Hh * 4);
  float* pg1f = (float*)alloc((size_t)R_PP * Bb * Hh * 4);
  float* po1f = (float*)alloc((size_t)R_PO * Bb * Oo * 4);
  unsigned* flags = (unsigned*)alloc(256 * FLAG_STRIDE * 4);   // 32 KB

  conv_kernel<<<1024, 256, 0, stream>>>(W_hh1, whh1, Hh * Hh);
  conv_kernel<<<1024, 256, 0, stream>>>(W_ih2, wih2, Hh * Hh);
  conv_kernel<<<1024, 256, 0, stream>>>(W_hh2, whh2, Hh * Hh);
  conv_kernel<<<2048, 256, 0, stream>>>(Wg,    wg,   Hh * 2 * Hh);
  conv_kernel<<<256,  256, 0, stream>>>(Wo1,   wo1,  Oo * Hh);
  conv_kernel<<<256,  256, 0, stream>>>(Wo2,   wo2,  Oo * Hh);
  init_kernel<<<512, 256, 0, stream>>>(h1ring, h2ring, h2f, flags);
  prex_kernel<<<8192, 256, 0, stream>>>(x, W_ih1, b_ih1, b_hh1, prex);

  RP p;
  p.h1ring = h1ring; p.h2ring = h2ring;
  p.h2f = h2f; p.pre2f = pre2f; p.pg1f = pg1f; p.po1f = po1f;
  p.prex = prex;
  p.whh1 = whh1; p.wih2 = wih2; p.whh2 = whh2;
  p.wg = wg; p.wo1 = wo1; p.wo2 = wo2;
  p.b_ih2 = b_ih2; p.b_hh2 = b_hh2;
  p.bg = bg; p.bo1 = bo1; p.bo2 = bo2;
  p.out = (float*)d_out;
  p.flags = flags;

  rnn_kernel<<<NBLK, 256, 0, stream>>>(p);
}

// Round 8
// 2692.942 us; speedup vs baseline: 1.9687x; 1.9687x over previous
//
#include <hip/hip_runtime.h>
#include <cstddef>

using bf16x8 = __attribute__((ext_vector_type(8))) short;
using f32x4  = __attribute__((ext_vector_type(4))) float;

constexpr int Bb = 128;
constexpr int Tt = 256;
constexpr int Hh = 1024;
constexpr int Oo = 64;
constexpr int NBLK = 200;         // 64 H1 + 32 P2 + 32 PG + 64 H2U + 4 PO + 4 ZO
constexpr int FLAG_STRIDE = 32;   // dwords -> 128B between flags
constexpr int RS = 1048;          // LDS row stride in shorts (bank-spread, proven)

// ring depths
constexpr int R_H1 = 8;
constexpr int R_H2 = 16;
constexpr int R_PP = 6;
constexpr int R_PO = 16;

// flag group bases
constexpr int FH1 = 0;    // 64 slots (bid 0-63)
constexpr int FP2 = 64;   // 32 slots (bid 64-95)
constexpr int FPG = 96;   // 32 slots (bid 96-127)
constexpr int FPO = 128;  // 4 slots  (bid 192-195)
constexpr int FH2 = 160;  // 64 slots (bid 128-191)
constexpr int FZO = 224;  // 4 slots  (bid 196-199)

__device__ __forceinline__ float bf2f(short s) {
  unsigned int u = ((unsigned int)(unsigned short)s) << 16;
  float f;
  __builtin_memcpy(&f, &u, 4);
  return f;
}
__device__ __forceinline__ short f2bf(float f) {
  unsigned int u;
  __builtin_memcpy(&u, &f, 4);
  u += 0x7fffu + ((u >> 16) & 1u);  // round-to-nearest-even
  return (short)(u >> 16);
}
__device__ __forceinline__ bf16x8 as_bf(int4 v) {
  union { int4 i; bf16x8 b; } u; u.i = v; return u.b;
}
__device__ __forceinline__ float ldf(const float* p) {
  return __hip_atomic_load((float*)p, __ATOMIC_RELAXED, __HIP_MEMORY_SCOPE_AGENT);
}
__device__ __forceinline__ void stf(float* p, float v) {
  __hip_atomic_store(p, v, __ATOMIC_RELAXED, __HIP_MEMORY_SCOPE_AGENT);
}
__device__ __forceinline__ unsigned ldu(const unsigned* p) {
  return __hip_atomic_load((unsigned*)p, __ATOMIC_RELAXED, __HIP_MEMORY_SCOPE_AGENT);
}

// Agent-scope (sc1) coherent 16B load — LLC-coherent (cross-XCD state reads).
#define LD16A(d, p) asm volatile("global_load_dwordx4 %0, %1, off sc1" \
                                 : "=v"(d) : "v"((const void*)(p)))

// Stage one 32-row x 1024-col bf16 state slab into LDS (256 thr x 16 loads).
__device__ __forceinline__ void stage_chunk(short* dstAs, const short* src, int tid) {
  const int row = tid >> 3;          // 0..31
  const int c0  = (tid & 7) * 8;     // shorts
  const short* gp = src + (size_t)row * Hh + c0;
  short* lp = dstAs + row * RS + c0;
  int4 r0[16];
#pragma unroll
  for (int j = 0; j < 16; ++j) LD16A(r0[j], gp + j * 64);
  asm volatile("s_waitcnt vmcnt(0)" ::: "memory");
#pragma unroll
  for (int j = 0; j < 16; ++j) *(int4*)(lp + j * 64) = r0[j];
}

// Load this wave's 16-col weight slice into 128 VGPRs (once, before t-loop).
// Layout matches MFMA B-operand: lane holds W[col=base+lm][k=q*8+c*32+0..7].
__device__ __forceinline__ void loadW(int4 (&w)[32], const short* B, size_t st,
                                      int lm, int q) {
  const short* bp = B + (size_t)lm * st + q * 8;
#pragma unroll
  for (int c = 0; c < 32; ++c) w[c] = *(const int4*)(bp + c * 32);
}

// K=1024 pass over a 32-row As chunk: 2 row-frags, 1 col-frag, W from regs.
__device__ __forceinline__ void passW2(const short* As32, int lm, int q,
    const int4 (&w)[32], f32x4& acc0, f32x4& acc1) {
  const short* ap0 = As32 + lm * RS + q * 8;
  const short* ap1 = ap0 + 16 * RS;
#pragma unroll
  for (int c = 0; c < 32; ++c) {
    const bf16x8 a0 = as_bf(*(const int4*)(ap0 + c * 32));
    const bf16x8 a1 = as_bf(*(const int4*)(ap1 + c * 32));
    const bf16x8 b  = as_bf(w[c]);
    acc0 = __builtin_amdgcn_mfma_f32_16x16x32_bf16(a0, b, acc0, 0, 0, 0);
    acc1 = __builtin_amdgcn_mfma_f32_16x16x32_bf16(a1, b, acc1, 0, 0, 0);
  }
}

// Dataflow sync: poll one producer group's flags until all >= gen (wave 0).
__device__ __forceinline__ void poll_ge(const unsigned* flags, int base,
                                        int mask, unsigned gen) {
  const unsigned* f = flags + (size_t)(base + (threadIdx.x & mask)) * FLAG_STRIDE;
  while (!__all(ldu(f) >= gen))
    __builtin_amdgcn_s_sleep(2);
}

// Release: all waves drain, block-sync, tid0 posts to this block's flag slot.
#define POST_FLAG(SLOT, GEN) do {                                          \
    asm volatile("s_waitcnt vmcnt(0) lgkmcnt(0)" ::: "memory");            \
    __syncthreads();                                                       \
    if (tid == 0)                                                          \
      __hip_atomic_store(p.flags + (size_t)(SLOT) * FLAG_STRIDE,           \
                         (unsigned)(GEN),                                  \
                         __ATOMIC_RELAXED, __HIP_MEMORY_SCOPE_AGENT);      \
  } while (0)

#define ST_BF16_PAIR(BASE, ROW, COL, HV) do {                              \
    const int _ov = __shfl_xor((int)(unsigned short)(HV), 1, 64);          \
    if ((lm & 1) == 0) {                                                   \
      const unsigned _pk = (unsigned)(unsigned short)(HV) | ((unsigned)_ov << 16); \
      __hip_atomic_store((unsigned*)((BASE) + (size_t)(ROW) * Hh + (COL)), _pk, \
                         __ATOMIC_RELAXED, __HIP_MEMORY_SCOPE_AGENT);      \
    } } while (0)

struct RP {
  short *h1ring;                    // 8  slots of [Bb x Hh] bf16
  short *h2ring;                    // 16 slots of [Bb x Hh] bf16
  float *h2f;                       // h2 f32 master (block-local tiles)
  float *pre2f;                     // 6 slots
  float *pg1f;                      // 6 slots
  float *po1f;                      // 16 slots of [Bb x Oo]
  const short* prex;
  const short *whh1, *wih2, *whh2, *wg, *wo1, *wo2;
  const float *b_ih2, *b_hh2, *bg, *bo1, *bo2;
  float* out;
  unsigned* flags;
};

// REGISTER-RESIDENT-WEIGHTS dataflow. Each wave owns 16 output cols; its
// 32KB weight slice lives in 128 VGPRs for all 256 steps (zero per-step
// B-feed — the r6->r7 slope showed B-streaming was ~8.5us of the 11.7us step).
// Dependency graph identical to r6 (ref-verified), flag slots remapped:
//   H1(t)  <- FH1>=t; [t>=8]  FP2,FPG >= t-7, FPO >= t-7      (h1 ring 8)
//   P2(t)  <- FH1>=t+1; [t>=6] FH2 >= t-5                     (pre2 ring 6)
//   PG(t)  <- FH1>=t+1; [t>=6] FH2 >= t-4                     (pg1 ring 6)
//   PO(t)  <- FH1>=t+1; [t>=16] FZO >= t-15                   (po1 ring 16)
//   H2U(s) <- FP2>=s+1; [s>=1] FPG>=s, FH2>=s; [s>=16] FZO>=s-15 (h2 ring 16)
//   ZO(ot) <- FH2>=ot+1, FPO>=ot+1
__global__ void __launch_bounds__(256, 1) rnn_kernel(RP p) {
  __shared__ short As[64 * RS];     // 134144 B (two 32-row chunks)
  __shared__ float zbuf[2048];      // 8 KB H2U z-exchange
  const int tid = threadIdx.x;
  const int lane = tid & 63;
  const int wv = tid >> 6;
  const int lm = lane & 15;
  const int q = lane >> 4;
  const int bid = blockIdx.x;

  const size_t HS = (size_t)Bb * Hh;
  const f32x4 z4 = {0.f, 0.f, 0.f, 0.f};
  int4 w[32];                       // this wave's weight slice (128 VGPR)

  if (bid < 64) {                      // ===== H1: 4rg x 16cg, 32r x 64c =====
    const int g = bid;
    const int mb = (g >> 4) * 32, cb = (g & 15) * 64;
    const int cw = cb + wv * 16;
    loadW(w, p.whh1 + (size_t)cw * Hh, Hh, lm, q);
    for (int t = 0; t < Tt; ++t) {
      short prs[2][4];
      const short* pr = p.prex + (size_t)t * HS;
#pragma unroll
      for (int rf = 0; rf < 2; ++rf)
#pragma unroll
        for (int r = 0; r < 4; ++r)
          prs[rf][r] = pr[(size_t)(mb + rf * 16 + q * 4 + r) * Hh + cw + lm];
      if (tid < 64) {
        if (t >= 1) poll_ge(p.flags, FH1, 63, (unsigned)t);
        if (t >= 8) {
          poll_ge(p.flags, FP2, 31, (unsigned)(t - 7));
          poll_ge(p.flags, FPG, 31, (unsigned)(t - 7));
          poll_ge(p.flags, FPO, 3,  (unsigned)(t - 7));
        }
      }
      __syncthreads();
      const short* h1prev = p.h1ring + (size_t)((t + R_H1 - 1) % R_H1) * HS;
      stage_chunk(As, h1prev + (size_t)mb * Hh, tid);
      __syncthreads();
      f32x4 a0 = z4, a1 = z4;
      passW2(As, lm, q, w, a0, a1);
      short* h1out = p.h1ring + (size_t)(t % R_H1) * HS;
#pragma unroll
      for (int rf = 0; rf < 2; ++rf)
#pragma unroll
        for (int r = 0; r < 4; ++r) {
          const int row = mb + rf * 16 + q * 4 + r;
          const float z = rf ? a1[r] : a0[r];
          const short hv = f2bf(tanhf(z + bf2f(prs[rf][r])));
          ST_BF16_PAIR(h1out, row, cw + lm, hv);
        }
      POST_FLAG(FH1 + g, t + 1);
    }
  } else if (bid < 128) {              // ===== P2 / PG: 2rg x 16cg, 64r x 64c =====
    const bool isP2 = (bid < 96);
    const int g = isP2 ? (bid - 64) : (bid - 96);
    const int mb = (g >> 4) * 64, cb = (g & 15) * 64;
    const int cw = cb + wv * 16;
    float bias;
    if (isP2) {
      bias = p.b_ih2[cw + lm] + p.b_hh2[cw + lm];
      loadW(w, p.wih2 + (size_t)cw * Hh, Hh, lm, q);
    } else {
      bias = p.bg[cw + lm];
      loadW(w, p.wg + (size_t)cw * (2 * Hh), 2 * Hh, lm, q);
    }
    const int fbase = isP2 ? FP2 : FPG;
    const int fslot = fbase + g;
    for (int t = 0; t < Tt; ++t) {
      if (tid < 64) {
        poll_ge(p.flags, FH1, 63, (unsigned)(t + 1));
        if (t >= R_PP) poll_ge(p.flags, FH2, 63, (unsigned)(t - (isP2 ? 5 : 4)));
      }
      __syncthreads();
      const short* h1cur = p.h1ring + (size_t)(t % R_H1) * HS;
      stage_chunk(As, h1cur + (size_t)mb * Hh, tid);
      stage_chunk(As + 32 * RS, h1cur + (size_t)(mb + 32) * Hh, tid);
      __syncthreads();
      f32x4 acc[4];
      acc[0] = acc[1] = acc[2] = acc[3] = (f32x4){bias, bias, bias, bias};
      passW2(As, lm, q, w, acc[0], acc[1]);
      passW2(As + 32 * RS, lm, q, w, acc[2], acc[3]);
      float* dst = (isP2 ? p.pre2f : p.pg1f) + (size_t)(t % R_PP) * HS;
#pragma unroll
      for (int rf = 0; rf < 4; ++rf)
#pragma unroll
        for (int r = 0; r < 4; ++r) {
          const int row = mb + rf * 16 + q * 4 + r;
          stf(dst + (size_t)row * Hh + cw + lm, acc[rf][r]);
        }
      POST_FLAG(fslot, t + 1);
    }
  } else if (bid < 192) {              // ===== H2U: 2rg x 32cg, 64r x 32c =====
    const int g = bid - 128;
    const int mb = (g >> 5) * 64, cb = (g & 31) * 32;
    const int m = wv >> 1;             // 0: z2 (whh2), 1: zg (wg2)
    const int ch = wv & 1;             // col half
    const int cw = cb + ch * 16;
    if (m == 0) loadW(w, p.whh2 + (size_t)cw * Hh, Hh, lm, q);
    else        loadW(w, p.wg + Hh + (size_t)cw * (2 * Hh), 2 * Hh, lm, q);
    for (int s = 0; s < Tt; ++s) {
      if (tid < 64) {
        poll_ge(p.flags, FP2, 31, (unsigned)(s + 1));
        if (s >= 1) {
          poll_ge(p.flags, FPG, 31, (unsigned)s);
          poll_ge(p.flags, FH2, 63, (unsigned)s);
        }
        if (s >= R_H2) poll_ge(p.flags, FZO, 3, (unsigned)(s - 15));
      }
      __syncthreads();
      float p2v[4][4], pg1v[4][4], hpv[4][4];
      if (m == 0) {
        const float* pre2s = p.pre2f + (size_t)(s % R_PP) * HS;
        const float* pg1s  = p.pg1f + (size_t)((s + R_PP - 1) % R_PP) * HS;
#pragma unroll
        for (int rf = 0; rf < 4; ++rf)
#pragma unroll
          for (int r = 0; r < 4; ++r) {
            const size_t idx = (size_t)(mb + rf * 16 + q * 4 + r) * Hh + cw + lm;
            p2v[rf][r] = ldf(pre2s + idx);
            pg1v[rf][r] = (s > 0) ? ldf(pg1s + idx) : 0.f;
            hpv[rf][r] = p.h2f[idx];     // block-local plain RW
          }
      }
      const short* h2prev = p.h2ring + (size_t)((s + R_H2 - 1) % R_H2) * HS;
      stage_chunk(As, h2prev + (size_t)mb * Hh, tid);
      stage_chunk(As + 32 * RS, h2prev + (size_t)(mb + 32) * Hh, tid);
      __syncthreads();
      f32x4 acc[4];
      acc[0] = acc[1] = acc[2] = acc[3] = z4;
      passW2(As, lm, q, w, acc[0], acc[1]);
      passW2(As + 32 * RS, lm, q, w, acc[2], acc[3]);
      if (m == 1) {                    // publish zg to wave (wv-2)
        float* zb = zbuf + ch * 1024;
#pragma unroll
        for (int rf = 0; rf < 4; ++rf)
#pragma unroll
          for (int r = 0; r < 4; ++r)
            zb[(rf * 4 + r) * 64 + lane] = acc[rf][r];
      }
      __syncthreads();
      if (m == 0) {
        const float* zb = zbuf + ch * 1024;
        short* h2out = p.h2ring + (size_t)(s % R_H2) * HS;
#pragma unroll
        for (int rf = 0; rf < 4; ++rf)
#pragma unroll
          for (int r = 0; r < 4; ++r) {
            const int row = mb + rf * 16 + q * 4 + r;
            const size_t idx = (size_t)row * Hh + cw + lm;
            const float zg = zb[(rf * 4 + r) * 64 + lane];
            const float u = (s == 0) ? 1.f
                : 1.f / (1.f + expf(-(zg + pg1v[rf][r])));
            const float hn = tanhf(acc[rf][r] + p2v[rf][r]);
            const float nv = fmaf(u, hn - hpv[rf][r], hpv[rf][r]);
            p.h2f[idx] = nv;
            const short hv = f2bf(nv);
            ST_BF16_PAIR(h2out, row, cw + lm, hv);
          }
      }
      POST_FLAG(FH2 + g, s + 1);
    }
  } else if (bid < 196) {              // ===== PO: 4rg, 32r x 64c =====
    const int g = bid - 192;
    const int mb = g * 32;
    const int cw = wv * 16;
    const float bias = p.bo1[cw + lm];
    loadW(w, p.wo1 + (size_t)cw * Hh, Hh, lm, q);
    for (int t = 0; t < Tt; ++t) {
      if (tid < 64) {
        poll_ge(p.flags, FH1, 63, (unsigned)(t + 1));
        if (t >= R_PO) poll_ge(p.flags, FZO, 3, (unsigned)(t - 15));
      }
      __syncthreads();
      const short* h1cur = p.h1ring + (size_t)(t % R_H1) * HS;
      stage_chunk(As, h1cur + (size_t)mb * Hh, tid);
      __syncthreads();
      f32x4 a0 = {bias, bias, bias, bias}, a1 = a0;
      passW2(As, lm, q, w, a0, a1);
      float* dst = p.po1f + (size_t)(t % R_PO) * (Bb * Oo);
#pragma unroll
      for (int rf = 0; rf < 2; ++rf)
#pragma unroll
        for (int r = 0; r < 4; ++r) {
          const int row = mb + rf * 16 + q * 4 + r;
          const float z = rf ? a1[r] : a0[r];
          stf(dst + (size_t)row * Oo + cw + lm, tanhf(z));
        }
      POST_FLAG(FPO + g, t + 1);
    }
  } else {                             // ===== ZO: 4rg, 32r x 64c =====
    const int g = bid - 196;
    const int mb = g * 32;
    const int cw = wv * 16;
    const float bias = p.bo2[cw + lm];
    loadW(w, p.wo2 + (size_t)cw * Hh, Hh, lm, q);
    for (int ot = 0; ot < Tt; ++ot) {
      if (tid < 64) {
        poll_ge(p.flags, FH2, 63, (unsigned)(ot + 1));
        poll_ge(p.flags, FPO, 3,  (unsigned)(ot + 1));
      }
      __syncthreads();
      float pv[2][4];
      const float* po1s = p.po1f + (size_t)(ot % R_PO) * (Bb * Oo);
#pragma unroll
      for (int rf = 0; rf < 2; ++rf)
#pragma unroll
        for (int r = 0; r < 4; ++r)
          pv[rf][r] = ldf(po1s + (size_t)(mb + rf * 16 + q * 4 + r) * Oo + cw + lm);
      const short* h2cur = p.h2ring + (size_t)(ot % R_H2) * HS;
      stage_chunk(As, h2cur + (size_t)mb * Hh, tid);
      __syncthreads();
      f32x4 a0 = {bias, bias, bias, bias}, a1 = a0;
      passW2(As, lm, q, w, a0, a1);
#pragma unroll
      for (int rf = 0; rf < 2; ++rf)
#pragma unroll
        for (int r = 0; r < 4; ++r) {
          const int row = mb + rf * 16 + q * 4 + r;
          const float z = rf ? a1[r] : a0[r];
          p.out[(size_t)row * (Tt * Oo) + (size_t)ot * Oo + cw + lm] =
              pv[rf][r] + tanhf(z);
        }
      POST_FLAG(FZO + g, ot + 1);
    }
  }
}

// pre_x[t][b][j] = x[b,t,:] @ W_ih1[j,:] + b_ih1[j] + b_hh1[j]  (stored bf16)
__global__ void __launch_bounds__(256) prex_kernel(
    const float* __restrict__ x, const float* __restrict__ wih1,
    const float* __restrict__ b_ih1, const float* __restrict__ b_hh1,
    short* __restrict__ prex) {
  const int tid = threadIdx.x;
  const int lane = tid & 63;
  const int wv = tid >> 6;
  const int lm = lane & 15;
  const int q = lane >> 4;
  const int bm = blockIdx.x >> 4;
  const int bn = blockIdx.x & 15;
  const int rowbase = bm * 64;
  const int col = bn * 64 + wv * 16 + lm;

  const f32x4 z4 = {0.f, 0.f, 0.f, 0.f};
  f32x4 acc[4];
#pragma unroll
  for (int mt = 0; mt < 4; ++mt) acc[mt] = z4;

#pragma unroll
  for (int kc = 0; kc < 2; ++kc) {
    const float* bp = wih1 + col * 64 + kc * 32 + q * 8;
    bf16x8 bf;
#pragma unroll
    for (int j = 0; j < 8; ++j) bf[j] = f2bf(bp[j]);
#pragma unroll
    for (int mt = 0; mt < 4; ++mt) {
      const float* ap = x + (size_t)(rowbase + mt * 16 + lm) * 64 + kc * 32 + q * 8;
      bf16x8 af;
#pragma unroll
      for (int j = 0; j < 8; ++j) af[j] = f2bf(ap[j]);
      acc[mt] = __builtin_amdgcn_mfma_f32_16x16x32_bf16(af, bf, acc[mt], 0, 0, 0);
    }
  }
  const float bia = b_ih1[col] + b_hh1[col];
#pragma unroll
  for (int mt = 0; mt < 4; ++mt) {
#pragma unroll
    for (int r = 0; r < 4; ++r) {
      const int row = rowbase + mt * 16 + q * 4 + r;  // row = b*256 + t
      const int b  = row >> 8;
      const int tt = row & 255;
      prex[((size_t)tt * Bb + b) * Hh + col] = f2bf(acc[mt][r] + bia);
    }
  }
}

__global__ void conv_kernel(const float* __restrict__ s, short* __restrict__ d, int n) {
  int i = blockIdx.x * blockDim.x + threadIdx.x;
  const int stride = gridDim.x * blockDim.x;
  for (; i < n; i += stride) d[i] = f2bf(s[i]);
}

__global__ void init_kernel(short* h1ring, short* h2ring,
                            float* h2f, unsigned* flags) {
  const int i = blockIdx.x * blockDim.x + threadIdx.x;  // exactly 128*1024
  const size_t HS = (size_t)Bb * Hh;
  h1ring[(size_t)(R_H1 - 1) * HS + i] = 0;   // h1(-1) slot
  h2ring[(size_t)(R_H2 - 1) * HS + i] = 0;   // h2(-1) slot
  h2f[i] = 0.f;
  if (i < 256) flags[i * FLAG_STRIDE] = 0u;
}

extern "C" void kernel_launch(void* const* d_in, const int* in_sizes, int n_in,
                              void* d_out, int out_size, void* d_ws, size_t ws_size,
                              hipStream_t stream) {
  (void)in_sizes; (void)n_in; (void)out_size; (void)ws_size;
  const float* x      = (const float*)d_in[0];
  const float* W_ih1  = (const float*)d_in[1];
  const float* b_ih1  = (const float*)d_in[2];
  const float* W_hh1  = (const float*)d_in[3];
  const float* b_hh1  = (const float*)d_in[4];
  const float* W_ih2  = (const float*)d_in[5];
  const float* b_ih2  = (const float*)d_in[6];
  const float* W_hh2  = (const float*)d_in[7];
  const float* b_hh2  = (const float*)d_in[8];
  const float* Wg     = (const float*)d_in[9];
  const float* bg     = (const float*)d_in[10];
  const float* Wo1    = (const float*)d_in[11];
  const float* bo1    = (const float*)d_in[12];
  const float* Wo2    = (const float*)d_in[13];
  const float* bo2    = (const float*)d_in[14];

  char* ws = (char*)d_ws;
  size_t off = 0;
  auto alloc = [&](size_t bytes) -> void* {
    void* ptr = ws + off;
    off += (bytes + 255) & ~(size_t)255;
    return ptr;
  };
  short* whh1 = (short*)alloc((size_t)Hh * Hh * 2);
  short* wih2 = (short*)alloc((size_t)Hh * Hh * 2);
  short* whh2 = (short*)alloc((size_t)Hh * Hh * 2);
  short* wg   = (short*)alloc((size_t)Hh * 2 * Hh * 2);
  short* wo1  = (short*)alloc((size_t)Oo * Hh * 2);
  short* wo2  = (short*)alloc((size_t)Oo * Hh * 2);
  short* prex = (short*)alloc((size_t)Bb * Tt * Hh * 2);
  short* h1ring = (short*)alloc((size_t)R_H1 * Bb * Hh * 2);
  short* h2ring = (short*)alloc((size_t)R_H2 * Bb * Hh * 2);
  float* h2f  = (float*)alloc((size_t)Bb * Hh * 4);
  float* pre2f= (float*)alloc((size_t)R_PP * Bb * Hh * 4);
  float* pg1f = (float*)alloc((size_t)R_PP * Bb * Hh * 4);
  float* po1f = (float*)alloc((size_t)R_PO * Bb * Oo * 4);
  unsigned* flags = (unsigned*)alloc(256 * FLAG_STRIDE * 4);   // 32 KB

  conv_kernel<<<1024, 256, 0, stream>>>(W_hh1, whh1, Hh * Hh);
  conv_kernel<<<1024, 256, 0, stream>>>(W_ih2, wih2, Hh * Hh);
  conv_kernel<<<1024, 256, 0, stream>>>(W_hh2, whh2, Hh * Hh);
  conv_kernel<<<2048, 256, 0, stream>>>(Wg,    wg,   Hh * 2 * Hh);
  conv_kernel<<<256,  256, 0, stream>>>(Wo1,   wo1,  Oo * Hh);
  conv_kernel<<<256,  256, 0, stream>>>(Wo2,   wo2,  Oo * Hh);
  init_kernel<<<512, 256, 0, stream>>>(h1ring, h2ring, h2f, flags);
  prex_kernel<<<8192, 256, 0, stream>>>(x, W_ih1, b_ih1, b_hh1, prex);

  RP p;
  p.h1ring = h1ring; p.h2ring = h2ring;
  p.h2f = h2f; p.pre2f = pre2f; p.pg1f = pg1f; p.po1f = po1f;
  p.prex = prex;
  p.whh1 = whh1; p.wih2 = wih2; p.whh2 = whh2;
  p.wg = wg; p.wo1 = wo1; p.wo2 = wo2;
  p.b_ih2 = b_ih2; p.b_hh2 = b_hh2;
  p.bg = bg; p.bo1 = bo1; p.bo2 = bo2;
  p.out = (float*)d_out;
  p.flags = flags;

  rnn_kernel<<<NBLK, 256, 0, stream>>>(p);
}